// Round 2
// baseline (360.097 us; speedup 1.0000x reference)
//
#include <hip/hip_runtime.h>

// BasicNCA: 16 sequential steps of (11x11 SAME conv -> per-pixel MLP 1->10->10->1
// -> residual add -> clip[0,1]) on (16,1,256,256) fp32.
// Output = all 17 states: out[t] slab, t=0..16, slab = 16*256*256 floats.
//
// Persistent-kernel version: ONE plain launch, 1024 blocks (4/CU, co-resident by
// __launch_bounds__(256,4) + 7.9KB LDS), software grid barrier in d_ws between
// steps. Host checks occupancy and falls back to the verified 17-launch path if
// co-residency isn't guaranteed. MLP uses an exact piecewise-linear collapse
// (valid because b1==0; runtime-checked, slow path kept).

#define HH 256
#define WW 256
#define BB 16
#define TH 16
#define TW 64
#define SH (TH + 10)   // 26
#define SW (TW + 10)   // 74
#define SWP 76         // padded LDS stride (16B-aligned rows)
#define SLAB (BB * HH * WW)
#define NSTEPS 16
#define NB 1024        // 4 x-tiles * 16 y-tiles * 16 batch

// ---------------- software grid barrier (accumulate-only counter) ----------------
__device__ __forceinline__ void grid_bar(unsigned* cnt, unsigned target) {
    __syncthreads();                       // all lds reads of this block done
    if (threadIdx.x == 0) {
        __threadfence();                   // release: slab writes visible agent-wide
        __hip_atomic_fetch_add(cnt, 1u, __ATOMIC_RELAXED, __HIP_MEMORY_SCOPE_AGENT);
        while (__hip_atomic_load(cnt, __ATOMIC_RELAXED, __HIP_MEMORY_SCOPE_AGENT) < target)
            __builtin_amdgcn_s_sleep(1);
        __threadfence();                   // acquire
    }
    __syncthreads();
}

// ---------------- PWL precompute: c+ = relu(w1) @ w2^T, c- = min(w1,0) @ w2^T ----
__device__ __forceinline__ void mlp_precompute(
    const float* __restrict__ w1, const float* __restrict__ b1,
    const float* __restrict__ w2, bool& fast, float (&cp)[10], float (&cn)[10]) {
    fast = true;
#pragma unroll
    for (int i = 0; i < 10; ++i) fast = fast && (b1[i] == 0.f);
#pragma unroll
    for (int o = 0; o < 10; ++o) { cp[o] = 0.f; cn[o] = 0.f; }
    if (fast) {
#pragma unroll
        for (int i = 0; i < 10; ++i) {
            float wi = w1[i];
            float p = fmaxf(wi, 0.f), n = fminf(wi, 0.f);
#pragma unroll
            for (int o = 0; o < 10; ++o) {
                cp[o] = fmaf(p, w2[o * 10 + i], cp[o]);
                cn[o] = fmaf(n, w2[o * 10 + i], cn[o]);
            }
        }
    }
}

// ---------------- one tile of one step (shared by persistent + fallback) --------
__device__ __forceinline__ void step_tile(
    const float* __restrict__ img, float* __restrict__ dst, float* __restrict__ t0,
    float* s, int gy0, int gx0, int tid, bool fast,
    const float (&cp)[10], const float (&cn)[10],
    const float* __restrict__ Kk,
    const float* __restrict__ w1, const float* __restrict__ b1,
    const float* __restrict__ w2, const float* __restrict__ b2,
    const float* __restrict__ w3, float b3v) {
    // stage halo'd tile (zero pad = SAME)
    for (int i = tid; i < SH * SW; i += 256) {
        int r = i / SW, c = i - r * SW;
        int gy = gy0 - 5 + r, gx = gx0 - 5 + c;
        float v = 0.f;
        if (gy >= 0 && gy < HH && gx >= 0 && gx < WW) v = img[gy * WW + gx];
        s[r * SWP + c] = v;
    }
    __syncthreads();

    const int tx = tid & 15, ty = tid >> 4;
    const int x0 = tx * 4;

    // 11x11 conv, 14-wide register sliding window per ky
    float acc0 = 0.f, acc1 = 0.f, acc2 = 0.f, acc3 = 0.f;
#pragma unroll
    for (int ky = 0; ky < 11; ++ky) {
        const float* row = &s[(ty + ky) * SWP + x0];
        float win[16];
        *(float4*)(win + 0)  = *(const float4*)(row + 0);
        *(float4*)(win + 4)  = *(const float4*)(row + 4);
        *(float4*)(win + 8)  = *(const float4*)(row + 8);
        *(float2*)(win + 12) = *(const float2*)(row + 12);
#pragma unroll
        for (int kx = 0; kx < 11; ++kx) {
            float kv = Kk[ky * 11 + kx];  // wave-uniform -> s_load
            acc0 = fmaf(win[kx + 0], kv, acc0);
            acc1 = fmaf(win[kx + 1], kv, acc1);
            acc2 = fmaf(win[kx + 2], kv, acc2);
            acc3 = fmaf(win[kx + 3], kv, acc3);
        }
    }

    float vacc[4] = {acc0, acc1, acc2, acc3};
    float res[4];
    if (fast) {
        // exact PWL collapse (b1==0): h2_o = relu(v * c_o^{sign(v)} + b2_o)
#pragma unroll
        for (int p = 0; p < 4; ++p) {
            float v = vacc[p];
            bool pos = (v >= 0.f);
            float y = b3v;
#pragma unroll
            for (int o = 0; o < 10; ++o) {
                float c = pos ? cp[o] : cn[o];
                float a = fmaf(v, c, b2[o]);
                y = fmaf(fmaxf(a, 0.f), w3[o], y);
            }
            float xc = s[(ty + 5) * SWP + x0 + 5 + p];
            res[p] = fminf(fmaxf(xc + y, 0.f), 1.f);
        }
    } else {
        // original exact path
#pragma unroll
        for (int p = 0; p < 4; ++p) {
            float v = vacc[p];
            float h1[10];
#pragma unroll
            for (int i = 0; i < 10; ++i)
                h1[i] = fmaxf(fmaf(v, w1[i], b1[i]), 0.f);
            float y = b3v;
#pragma unroll
            for (int o = 0; o < 10; ++o) {
                float a = b2[o];
#pragma unroll
                for (int i = 0; i < 10; ++i)
                    a = fmaf(h1[i], w2[o * 10 + i], a);
                y = fmaf(fmaxf(a, 0.f), w3[o], y);
            }
            float xc = s[(ty + 5) * SWP + x0 + 5 + p];
            res[p] = fminf(fmaxf(xc + y, 0.f), 1.f);
        }
    }

    if (t0) {  // write t=0 slab from the staged tile (only at k==0)
        const float* c0 = &s[(ty + 5) * SWP + x0 + 5];
        float* o0 = t0 + (gy0 + ty) * WW + gx0 + x0;
        *(float4*)o0 = make_float4(c0[0], c0[1], c0[2], c0[3]);
    }
    float* orow = dst + (gy0 + ty) * WW + gx0 + x0;
    *(float4*)orow = make_float4(res[0], res[1], res[2], res[3]);
}

// ---------------- persistent fused kernel ----------------
__global__ __launch_bounds__(256, 4) void nca_persist(
    const float* __restrict__ x, float* __restrict__ out, unsigned* cnt,
    const float* __restrict__ Kk,
    const float* __restrict__ w1, const float* __restrict__ b1,
    const float* __restrict__ w2, const float* __restrict__ b2,
    const float* __restrict__ w3, const float* __restrict__ b3) {
    __shared__ __align__(16) float s[SH * SWP];
    const int tid = threadIdx.x;
    const int bid = blockIdx.x;
    const int gx0 = (bid & 3) * TW;
    const int gy0 = ((bid >> 2) & 15) * TH;
    const int b   = bid >> 6;
    const float b3v = b3[0];

    bool fast; float cp[10], cn[10];
    mlp_precompute(w1, b1, w2, fast, cp, cn);

    for (int k = 0; k < NSTEPS; ++k) {
        if (k > 0) grid_bar(cnt, (unsigned)(NB * k));
        const float* img = (k == 0 ? x : out + (size_t)k * SLAB) + b * HH * WW;
        float* dst = out + (size_t)(k + 1) * SLAB + b * HH * WW;
        float* t0  = (k == 0) ? out + b * HH * WW : nullptr;
        step_tile(img, dst, t0, s, gy0, gx0, tid, fast, cp, cn,
                  Kk, w1, b1, w2, b2, w3, b3v);
    }
}

// ---------------- fallback: verified 17-launch path ----------------
__global__ __launch_bounds__(256) void nca_copy_x(const float* __restrict__ x,
                                                  float* __restrict__ out) {
    int i = (blockIdx.x * 256 + threadIdx.x) * 4;
    *(float4*)(out + i) = *(const float4*)(x + i);
}

__global__ __launch_bounds__(256) void nca_step(
    const float* __restrict__ src, float* __restrict__ dst,
    const float* __restrict__ Kk,
    const float* __restrict__ w1, const float* __restrict__ b1,
    const float* __restrict__ w2, const float* __restrict__ b2,
    const float* __restrict__ w3, const float* __restrict__ b3) {
    __shared__ __align__(16) float s[SH * SWP];
    const int tid = threadIdx.x;
    const int b   = blockIdx.z;
    const int gy0 = blockIdx.y * TH;
    const int gx0 = blockIdx.x * TW;
    const float b3v = b3[0];
    bool fast; float cp[10], cn[10];
    mlp_precompute(w1, b1, w2, fast, cp, cn);
    step_tile(src + b * HH * WW, dst + b * HH * WW, nullptr, s, gy0, gx0, tid,
              fast, cp, cn, Kk, w1, b1, w2, b2, w3, b3v);
}

extern "C" void kernel_launch(void* const* d_in, const int* in_sizes, int n_in,
                              void* d_out, int out_size, void* d_ws, size_t ws_size,
                              hipStream_t stream) {
    const float* x  = (const float*)d_in[0];
    const float* Kk = (const float*)d_in[1];
    const float* w1 = (const float*)d_in[2];
    const float* b1 = (const float*)d_in[3];
    const float* w2 = (const float*)d_in[4];
    const float* b2 = (const float*)d_in[5];
    const float* w3 = (const float*)d_in[6];
    const float* b3 = (const float*)d_in[7];
    float* out = (float*)d_out;

    static int maxb = -1;
    if (maxb < 0) {
        if (hipOccupancyMaxActiveBlocksPerMultiprocessor(
                &maxb, (const void*)nca_persist, 256, 0) != hipSuccess)
            maxb = 0;
    }

    if (maxb >= 4 && d_ws != nullptr && ws_size >= 64) {
        hipMemsetAsync(d_ws, 0, 64, stream);  // reset barrier counter each launch
        nca_persist<<<NB, 256, 0, stream>>>(x, out, (unsigned*)d_ws,
                                            Kk, w1, b1, w2, b2, w3, b3);
    } else {
        nca_copy_x<<<SLAB / (256 * 4), 256, 0, stream>>>(x, out);
        dim3 grid(WW / TW, HH / TH, BB);
        for (int k = 0; k < 16; ++k) {
            nca_step<<<grid, 256, 0, stream>>>(out + (size_t)k * SLAB,
                                               out + (size_t)(k + 1) * SLAB,
                                               Kk, w1, b1, w2, b2, w3, b3);
        }
    }
}